// Round 12
// baseline (28.843 us; speedup 1.0000x reference)
//
#include <hip/hip_runtime.h>
#include <hip/hip_fp16.h>

#define SCALE 0.0625f

constexpr int HF = 64, WF = 64, CF = 256, BF = 8;
constexpr int P = 7, S = 4;
constexpr int BINS = P * P;                 // 49
constexpr int NROI = 256;
constexpr int NBIN_TOT = NROI * BINS;       // 12544
constexpr int POOL_BLOCKS = NBIN_TOT / 4;   // 3136
constexpr int CHUNK = POOL_BLOCKS / 8;      // 392 (XCD swizzle)
constexpr int TBLK = 2048;                  // 64x64 transpose tiles
constexpr int SETUP_BLK = NBIN_TOT / 256;   // 49 param blocks
constexpr size_t XT_HALFS   = (size_t)BF * CF * HF * WF;     // 2^23 halves
constexpr size_t PAR_FLOATS = (size_t)NBIN_TOT * 16;

// ---------------------------------------------------------------------------
// per-bin separable weights (proven R3-R10)
// ---------------------------------------------------------------------------
__device__ __forceinline__ void compute_params(int t, const float* __restrict__ rois,
                                               const float* __restrict__ offset,
                                               float* __restrict__ params) {
    const int n   = t / BINS;
    const int bin = t - n * BINS;
    const int ph  = bin / 7;
    const int pw  = bin - ph * 7;

    const float* r = rois + n * 5;
    const int   batch  = (int)r[0];
    const float roi_sw = rintf(r[1]) * SCALE - 0.5f;   // rintf == jnp.round (half-even)
    const float roi_sh = rintf(r[2]) * SCALE - 0.5f;
    const float roi_w  = fmaxf((rintf(r[3]) + 1.0f) * SCALE - 0.5f - roi_sw, 0.1f);
    const float roi_h  = fmaxf((rintf(r[4]) + 1.0f) * SCALE - 0.5f - roi_sh, 0.1f);
    const float bin_w  = roi_w / 7.0f;
    const float bin_h  = roi_h / 7.0f;
    const float sub_w  = bin_w * 0.25f;
    const float sub_h  = bin_h * 0.25f;

    const float tx = offset[n * 98 + bin] * 0.1f;
    const float ty = offset[n * 98 + 49 + bin] * 0.1f;
    const float wstart = (float)pw * bin_w + roi_sw + tx * roi_w;
    const float hstart = (float)ph * bin_h + roi_sh + ty * roi_h;

    float WX0 = 0.f, WX1 = 0.f, WX2 = 0.f, WX3 = 0.f, cw = 0.f;
    const int xbase = (int)fminf(fmaxf(wstart, 0.f), 63.f);
    #pragma unroll
    for (int i = 0; i < 4; ++i) {
        const float p  = wstart + (float)i * sub_w;
        const float vf = (p >= -0.5f && p <= 63.5f) ? 1.f : 0.f;
        cw += vf;
        const float pc = fminf(fmaxf(p, 0.f), 63.f);
        const float fx = floorf(pc);
        const float dx = pc - fx;
        const int   j  = (int)fx - xbase;
        const float lo = vf * (1.f - dx);
        const float hi = vf * dx;
        if (j == 0)      { WX0 += lo; WX1 += hi; }
        else if (j == 1) { WX1 += lo; WX2 += hi; }
        else if (j == 2) { WX2 += lo; WX3 += hi; }
        else             { WX3 += lo; }
    }
    float WY0 = 0.f, WY1 = 0.f, WY2 = 0.f, WY3 = 0.f, chh = 0.f;
    const int ybase = (int)fminf(fmaxf(hstart, 0.f), 63.f);
    #pragma unroll
    for (int i = 0; i < 4; ++i) {
        const float p  = hstart + (float)i * sub_h;
        const float vf = (p >= -0.5f && p <= 63.5f) ? 1.f : 0.f;
        chh += vf;
        const float pc = fminf(fmaxf(p, 0.f), 63.f);
        const float fy = floorf(pc);
        const float dy = pc - fy;
        const int   j  = (int)fy - ybase;
        const float lo = vf * (1.f - dy);
        const float hi = vf * dy;
        if (j == 0)      { WY0 += lo; WY1 += hi; }
        else if (j == 1) { WY1 += lo; WY2 += hi; }
        else if (j == 2) { WY2 += lo; WY3 += hi; }
        else             { WY3 += lo; }
    }

    const float cf  = cw * chh;
    const float inv = (cf > 0.f) ? (1.0f / cf) : 0.0f;

    float4* pp = (float4*)(params + ((size_t)t << 4));
    pp[0] = make_float4(WX0, WX1, WX2, WX3);
    pp[1] = make_float4(WY0, WY1, WY2, WY3);
    pp[2] = make_float4(inv, __int_as_float(batch),
                        __int_as_float(xbase), __int_as_float(ybase));
}

// ---------------------------------------------------------------------------
// Kernel 1 (fused): blocks [0,2048) transpose f32 BCHW -> fp16 BHWC;
// blocks [2048,2097) per-bin params; block 2097: deterministic stable
// rank-sort of rois by batch (roi_order[rank] = n) for XCD L2 locality.
// ---------------------------------------------------------------------------
__global__ __launch_bounds__(256) void fused_setup(const float* __restrict__ in,
                                                   const float* __restrict__ rois,
                                                   const float* __restrict__ offset,
                                                   __half* __restrict__ xt,
                                                   float* __restrict__ params,
                                                   int* __restrict__ roi_order) {
    __shared__ float sm[64 * 65];
    if (blockIdx.x < TBLK) {
        const int f   = blockIdx.x;
        const int hw0 = (f & 63) << 6;
        const int c0  = ((f >> 6) & 3) << 6;
        const int b   = f >> 8;
        const int tid = threadIdx.x;
        {
            const int t4 = (tid & 15) << 2;
            const int cr = tid >> 4;
            #pragma unroll
            for (int i = 0; i < 64; i += 16) {
                const float4 v = *(const float4*)(in +
                    ((size_t)(b * CF + c0 + cr + i)) * (HF * WF) + hw0 + t4);
                float* tp = &sm[(cr + i) * 65 + t4];
                tp[0] = v.x; tp[1] = v.y; tp[2] = v.z; tp[3] = v.w;
            }
        }
        __syncthreads();
        {
            __half* dst = xt + ((size_t)b * (HF * WF) + hw0) * CF + c0;
            const int cp  = tid & 31;
            const int hwl = tid >> 5;
            #pragma unroll
            for (int i = 0; i < 64; i += 8) {
                const int hw = hwl + i;
                const __half2 v = __floats2half2_rn(sm[(2 * cp) * 65 + hw],
                                                    sm[(2 * cp + 1) * 65 + hw]);
                *(__half2*)(dst + (size_t)hw * CF + 2 * cp) = v;
            }
        }
        return;
    }
    if (blockIdx.x < TBLK + SETUP_BLK) {
        const int t = ((int)blockIdx.x - TBLK) * 256 + (int)threadIdx.x;
        compute_params(t, rois, offset, params);
        return;
    }
    // ---- roi sort by batch (1 block, 256 threads, O(N^2) rank — stable) ----
    {
        int* keys = (int*)sm;
        const int n = threadIdx.x;
        keys[n] = (int)rois[n * 5];
        __syncthreads();
        const int kn = keys[n];
        int rank = 0;
        for (int m = 0; m < NROI; ++m) {
            const int km = keys[m];
            rank += (km < kn) || (km == kn && m < n);
        }
        roi_order[rank] = n;
    }
}

// ---------------------------------------------------------------------------
// Kernel 2: gather pool (R7/R10-proven body). Wave per SORTED bin:
// swizzled block chunk -> XCD; sorted order -> each XCD's ~32 rois span
// ~1-2 batches -> xt working set 2-4MB -> L2-resident gathers.
// ---------------------------------------------------------------------------
__global__ __launch_bounds__(256) void dcn_pool_gather(const __half* __restrict__ xt,
                                                       const float* __restrict__ params,
                                                       const int* __restrict__ roi_order,
                                                       float* __restrict__ out) {
    __shared__ float stage[4][264];
    const int tid  = threadIdx.x;
    const int lane = tid & 63;
    const int wv   = tid >> 6;
    int bid = blockIdx.x;
    bid = (bid & 7) * CHUNK + (bid >> 3);          // XCD j <- sorted chunk j
    const int gs  = (bid << 2) + wv;               // sorted bin id
    const int rs  = gs / BINS;
    const int bin = gs - rs * BINS;
    const int n   = roi_order[rs];                 // actual roi
    const int g   = n * BINS + bin;                // original bin id (params index)

    const float4* pp = (const float4*)(params + ((size_t)g << 4));
    const float4 WX = pp[0];
    const float4 WY = pp[1];
    const float4 M  = pp[2];
    const float inv   = M.x;
    const int   batch = __float_as_int(M.y);
    const int   xbase = __float_as_int(M.z);
    const int   ybase = __float_as_int(M.w);

    const int half_ = lane >> 5;
    const int oct   = lane & 31;
    const __half* bp = xt + ((size_t)batch << 20) + (oct << 3);

    const int xi0 = xbase << 8;
    const int xi1 = min(xbase + 1, 63) << 8;
    const int xi2 = min(xbase + 2, 63) << 8;
    const int xi3 = min(xbase + 3, 63) << 8;
    const bool c3 = (WX.w != 0.f);

    float a0 = 0.f, a1 = 0.f, a2 = 0.f, a3 = 0.f;
    float a4 = 0.f, a5 = 0.f, a6 = 0.f, a7 = 0.f;

#define DCN_CELL(wgt, xi)                                                            \
    {                                                                                \
        union { uint4 u; __half2 h[4]; } U;                                          \
        U.u = *(const uint4*)(rp + xi);                                              \
        float2 f_;                                                                   \
        f_ = __half22float2(U.h[0]); a0 = fmaf(wgt, f_.x, a0); a1 = fmaf(wgt, f_.y, a1); \
        f_ = __half22float2(U.h[1]); a2 = fmaf(wgt, f_.x, a2); a3 = fmaf(wgt, f_.y, a3); \
        f_ = __half22float2(U.h[2]); a4 = fmaf(wgt, f_.x, a4); a5 = fmaf(wgt, f_.y, a5); \
        f_ = __half22float2(U.h[3]); a6 = fmaf(wgt, f_.x, a6); a7 = fmaf(wgt, f_.y, a7); \
    }

    // wave-uniform row-pair skip (no divergence; loads stay batched)
#define DCN_PAIR(wy_lo, wy_hi, cy0)                                                  \
    if (wy_lo != 0.f || wy_hi != 0.f) {                                              \
        const float wy = half_ ? (wy_hi) : (wy_lo);                                  \
        const __half* rp = bp + ((size_t)min(ybase + (cy0) + half_, 63) << 14);      \
        DCN_CELL(wy * WX.x, xi0)                                                     \
        DCN_CELL(wy * WX.y, xi1)                                                     \
        DCN_CELL(wy * WX.z, xi2)                                                     \
        if (c3) DCN_CELL(wy * WX.w, xi3)                                             \
    }

    DCN_PAIR(WY.x, WY.y, 0)
    DCN_PAIR(WY.z, WY.w, 2)
#undef DCN_PAIR
#undef DCN_CELL

    a0 += __shfl_xor(a0, 32); a1 += __shfl_xor(a1, 32);
    a2 += __shfl_xor(a2, 32); a3 += __shfl_xor(a3, 32);
    a4 += __shfl_xor(a4, 32); a5 += __shfl_xor(a5, 32);
    a6 += __shfl_xor(a6, 32); a7 += __shfl_xor(a7, 32);

    // conflict-free stage write: slot = oct + (half<<5)
    const float4 v = half_ ? make_float4(a4 * inv, a5 * inv, a6 * inv, a7 * inv)
                           : make_float4(a0 * inv, a1 * inv, a2 * inv, a3 * inv);
    ((float4*)stage[wv])[oct + (half_ << 5)] = v;
    __syncthreads();

    // channel c lives at float index fi(c) = ((c>>3)<<2) | ((c&4)<<5) | (c&3)
    const int base_gs = bid << 2;
    #pragma unroll
    for (int k = 0; k < 4; ++k) {
        const int idx = (k << 8) + tid;
        const int c    = idx >> 2;
        const int bs   = idx & 3;
        const int fi   = ((c >> 3) << 2) | ((c & 4) << 5) | (c & 3);
        const int gg_s = base_gs + bs;
        const int rr   = gg_s / BINS;
        const int bb2  = gg_s - rr * BINS;
        const int nn   = roi_order[rr];
        out[(size_t)nn * (CF * BINS) + c * BINS + bb2] = stage[bs][fi];
    }
}

// ---------------------------------------------------------------------------
// Fallback: direct (B,C,H,W) f32 gather (ws too small / unexpected shapes).
// ---------------------------------------------------------------------------
__global__ __launch_bounds__(256) void dcn_pool_fallback(const float* __restrict__ x,
                                                         const float* __restrict__ rois,
                                                         const float* __restrict__ offset,
                                                         float* __restrict__ out) {
    const int n   = blockIdx.x / BINS;
    const int bin = blockIdx.x % BINS;
    const int ph  = bin / P;
    const int pw  = bin % P;
    const int c   = threadIdx.x;

    const float* r = rois + n * 5;
    const int   batch  = (int)r[0];
    const float roi_sw = rintf(r[1]) * SCALE - 0.5f;
    const float roi_sh = rintf(r[2]) * SCALE - 0.5f;
    const float roi_w  = fmaxf((rintf(r[3]) + 1.0f) * SCALE - 0.5f - roi_sw, 0.1f);
    const float roi_h  = fmaxf((rintf(r[4]) + 1.0f) * SCALE - 0.5f - roi_sh, 0.1f);
    const float bin_w  = roi_w / 7.0f;
    const float bin_h  = roi_h / 7.0f;
    const float sub_w  = bin_w * 0.25f;
    const float sub_h  = bin_h * 0.25f;

    const float tx = offset[n * 98 + ph * 7 + pw] * 0.1f;
    const float ty = offset[n * 98 + 49 + ph * 7 + pw] * 0.1f;
    const float wstart = (float)pw * bin_w + roi_sw + tx * roi_w;
    const float hstart = (float)ph * bin_h + roi_sh + ty * roi_h;

    float sum = 0.0f;
    int   cnt = 0;
    for (int ih = 0; ih < S; ++ih) {
        for (int iw = 0; iw < S; ++iw) {
            const float wpos = wstart + (float)iw * sub_w;
            const float hpos = hstart + (float)ih * sub_h;
            if (wpos >= -0.5f && wpos <= (float)WF - 0.5f &&
                hpos >= -0.5f && hpos <= (float)HF - 0.5f) {
                const float wc_ = fminf(fmaxf(wpos, 0.0f), (float)(WF - 1));
                const float hc_ = fminf(fmaxf(hpos, 0.0f), (float)(HF - 1));
                const float fx = floorf(wc_);
                const float fy = floorf(hc_);
                const int x0 = (int)fx, x1i = (int)ceilf(wc_);
                const int y0 = (int)fy, y1i = (int)ceilf(hc_);
                const float dx = wc_ - fx, dy = hc_ - fy;
                const float* bbp = x + ((size_t)batch * CF + c) * (HF * WF);
                sum += (1.0f - dx) * (1.0f - dy) * bbp[y0 * WF + x0]
                     + dx * (1.0f - dy) * bbp[y0 * WF + x1i]
                     + (1.0f - dx) * dy * bbp[y1i * WF + x0]
                     + dx * dy * bbp[y1i * WF + x1i];
                ++cnt;
            }
        }
    }
    out[((size_t)n * CF + c) * BINS + bin] = (cnt > 0) ? (sum / (float)cnt) : 0.0f;
}

extern "C" void kernel_launch(void* const* d_in, const int* in_sizes, int n_in,
                              void* d_out, int out_size, void* d_ws, size_t ws_size,
                              hipStream_t stream) {
    const float* x      = (const float*)d_in[0];
    const float* rois   = (const float*)d_in[1];
    const float* offset = (const float*)d_in[2];
    float*       out    = (float*)d_out;

    const int N = in_sizes[1] / 5;
    const size_t need = XT_HALFS * sizeof(__half) + PAR_FLOATS * sizeof(float)
                      + NROI * sizeof(int);

    if (ws_size >= need && N == NROI) {
        __half* xt       = (__half*)d_ws;
        float*  params   = (float*)(xt + XT_HALFS);
        int*    roi_order = (int*)(params + PAR_FLOATS);
        fused_setup<<<TBLK + SETUP_BLK + 1, 256, 0, stream>>>(x, rois, offset,
                                                              xt, params, roi_order);
        dcn_pool_gather<<<POOL_BLOCKS, 256, 0, stream>>>(xt, params, roi_order, out);
    } else {
        dcn_pool_fallback<<<N * BINS, 256, 0, stream>>>(x, rois, offset, out);
    }
}

// Round 13
// 24.599 us; speedup vs baseline: 1.1725x; 1.1725x over previous
//
#include <hip/hip_runtime.h>
#include <hip/hip_fp16.h>

#define SCALE 0.0625f

constexpr int HF = 64, WF = 64, CF = 256, BF = 8;
constexpr int P = 7, S = 4;
constexpr int BINS = P * P;                 // 49
constexpr int NROI = 256;
constexpr int NBIN_TOT = NROI * BINS;       // 12544
constexpr int POOL_BLOCKS = NBIN_TOT / 4;   // 3136
constexpr int CHUNK = POOL_BLOCKS / 8;      // 392 (XCD swizzle)
constexpr int TBLK = 2048;                  // 64x64 transpose tiles
constexpr int SETUP_BLK = NBIN_TOT / 256;   // 49 param blocks
constexpr size_t XT_HALFS   = (size_t)BF * CF * HF * WF;     // 2^23 halves
constexpr size_t PAR_FLOATS = (size_t)NBIN_TOT * 16;

// ---------------------------------------------------------------------------
// per-bin separable weights (proven R3-R10)
// ---------------------------------------------------------------------------
__device__ __forceinline__ void compute_params(int t, const float* __restrict__ rois,
                                               const float* __restrict__ offset,
                                               float* __restrict__ params) {
    const int n   = t / BINS;
    const int bin = t - n * BINS;
    const int ph  = bin / 7;
    const int pw  = bin - ph * 7;

    const float* r = rois + n * 5;
    const int   batch  = (int)r[0];
    const float roi_sw = rintf(r[1]) * SCALE - 0.5f;   // rintf == jnp.round (half-even)
    const float roi_sh = rintf(r[2]) * SCALE - 0.5f;
    const float roi_w  = fmaxf((rintf(r[3]) + 1.0f) * SCALE - 0.5f - roi_sw, 0.1f);
    const float roi_h  = fmaxf((rintf(r[4]) + 1.0f) * SCALE - 0.5f - roi_sh, 0.1f);
    const float bin_w  = roi_w / 7.0f;
    const float bin_h  = roi_h / 7.0f;
    const float sub_w  = bin_w * 0.25f;
    const float sub_h  = bin_h * 0.25f;

    const float tx = offset[n * 98 + bin] * 0.1f;
    const float ty = offset[n * 98 + 49 + bin] * 0.1f;
    const float wstart = (float)pw * bin_w + roi_sw + tx * roi_w;
    const float hstart = (float)ph * bin_h + roi_sh + ty * roi_h;

    float WX0 = 0.f, WX1 = 0.f, WX2 = 0.f, WX3 = 0.f, cw = 0.f;
    const int xbase = (int)fminf(fmaxf(wstart, 0.f), 63.f);
    #pragma unroll
    for (int i = 0; i < 4; ++i) {
        const float p  = wstart + (float)i * sub_w;
        const float vf = (p >= -0.5f && p <= 63.5f) ? 1.f : 0.f;
        cw += vf;
        const float pc = fminf(fmaxf(p, 0.f), 63.f);
        const float fx = floorf(pc);
        const float dx = pc - fx;
        const int   j  = (int)fx - xbase;
        const float lo = vf * (1.f - dx);
        const float hi = vf * dx;
        if (j == 0)      { WX0 += lo; WX1 += hi; }
        else if (j == 1) { WX1 += lo; WX2 += hi; }
        else if (j == 2) { WX2 += lo; WX3 += hi; }
        else             { WX3 += lo; }
    }
    float WY0 = 0.f, WY1 = 0.f, WY2 = 0.f, WY3 = 0.f, chh = 0.f;
    const int ybase = (int)fminf(fmaxf(hstart, 0.f), 63.f);
    #pragma unroll
    for (int i = 0; i < 4; ++i) {
        const float p  = hstart + (float)i * sub_h;
        const float vf = (p >= -0.5f && p <= 63.5f) ? 1.f : 0.f;
        chh += vf;
        const float pc = fminf(fmaxf(p, 0.f), 63.f);
        const float fy = floorf(pc);
        const float dy = pc - fy;
        const int   j  = (int)fy - ybase;
        const float lo = vf * (1.f - dy);
        const float hi = vf * dy;
        if (j == 0)      { WY0 += lo; WY1 += hi; }
        else if (j == 1) { WY1 += lo; WY2 += hi; }
        else if (j == 2) { WY2 += lo; WY3 += hi; }
        else             { WY3 += lo; }
    }

    const float cf  = cw * chh;
    const float inv = (cf > 0.f) ? (1.0f / cf) : 0.0f;

    float4* pp = (float4*)(params + ((size_t)t << 4));
    pp[0] = make_float4(WX0, WX1, WX2, WX3);
    pp[1] = make_float4(WY0, WY1, WY2, WY3);
    pp[2] = make_float4(inv, __int_as_float(batch),
                        __int_as_float(xbase), __int_as_float(ybase));
}

// ---------------------------------------------------------------------------
// Kernel 1 (fused): blocks [0,2048) transpose f32 BCHW -> fp16 BHWC (64x64
// tiles, float4 loads); blocks [2048,2097) per-bin params. (R8-proven)
// ---------------------------------------------------------------------------
__global__ __launch_bounds__(256) void fused_setup(const float* __restrict__ in,
                                                   const float* __restrict__ rois,
                                                   const float* __restrict__ offset,
                                                   __half* __restrict__ xt,
                                                   float* __restrict__ params) {
    __shared__ float sm[64 * 65];
    if (blockIdx.x < TBLK) {
        const int f   = blockIdx.x;
        const int hw0 = (f & 63) << 6;
        const int c0  = ((f >> 6) & 3) << 6;
        const int b   = f >> 8;
        const int tid = threadIdx.x;
        {
            const int t4 = (tid & 15) << 2;
            const int cr = tid >> 4;
            #pragma unroll
            for (int i = 0; i < 64; i += 16) {
                const float4 v = *(const float4*)(in +
                    ((size_t)(b * CF + c0 + cr + i)) * (HF * WF) + hw0 + t4);
                float* tp = &sm[(cr + i) * 65 + t4];
                tp[0] = v.x; tp[1] = v.y; tp[2] = v.z; tp[3] = v.w;
            }
        }
        __syncthreads();
        {
            __half* dst = xt + ((size_t)b * (HF * WF) + hw0) * CF + c0;
            const int cp  = tid & 31;
            const int hwl = tid >> 5;
            #pragma unroll
            for (int i = 0; i < 64; i += 8) {
                const int hw = hwl + i;
                const __half2 v = __floats2half2_rn(sm[(2 * cp) * 65 + hw],
                                                    sm[(2 * cp + 1) * 65 + hw]);
                *(__half2*)(dst + (size_t)hw * CF + 2 * cp) = v;
            }
        }
        return;
    }
    const int t = ((int)blockIdx.x - TBLK) * 256 + (int)threadIdx.x;
    compute_params(t, rois, offset, params);
}

// ---------------------------------------------------------------------------
// Kernel 2: gather pool (R7-proven structure, 24.6us). Wave per bin:
// lane = (row-of-pair = lane>>5, channel-octet = lane&31), uint4 fp16x8 loads,
// wave-uniform row skip, 4 bins/block (256 thr). Stage slot = oct+(half<<5)
// (conflict-free); read remaps c -> fi(c) (2-way, free).
// ---------------------------------------------------------------------------
__global__ __launch_bounds__(256) void dcn_pool_gather(const __half* __restrict__ xt,
                                                       const float* __restrict__ params,
                                                       float* __restrict__ out) {
    __shared__ float stage[4][264];
    const int tid  = threadIdx.x;
    const int lane = tid & 63;
    const int wv   = tid >> 6;
    int bid = blockIdx.x;
    bid = (bid & 7) * CHUNK + (bid >> 3);          // bijective XCD swizzle
    const int g = (bid << 2) + wv;                 // global bin id

    const float4* pp = (const float4*)(params + ((size_t)g << 4));
    const float4 WX = pp[0];
    const float4 WY = pp[1];
    const float4 M  = pp[2];
    const float inv   = M.x;
    const int   batch = __float_as_int(M.y);
    const int   xbase = __float_as_int(M.z);
    const int   ybase = __float_as_int(M.w);

    const int half_ = lane >> 5;
    const int oct   = lane & 31;
    const __half* bp = xt + ((size_t)batch << 20) + (oct << 3);

    const int xi0 = xbase << 8;
    const int xi1 = min(xbase + 1, 63) << 8;
    const int xi2 = min(xbase + 2, 63) << 8;
    const int xi3 = min(xbase + 3, 63) << 8;
    const bool c3 = (WX.w != 0.f);

    float a0 = 0.f, a1 = 0.f, a2 = 0.f, a3 = 0.f;
    float a4 = 0.f, a5 = 0.f, a6 = 0.f, a7 = 0.f;

#define DCN_CELL(wgt, xi)                                                            \
    {                                                                                \
        union { uint4 u; __half2 h[4]; } U;                                          \
        U.u = *(const uint4*)(rp + xi);                                              \
        float2 f_;                                                                   \
        f_ = __half22float2(U.h[0]); a0 = fmaf(wgt, f_.x, a0); a1 = fmaf(wgt, f_.y, a1); \
        f_ = __half22float2(U.h[1]); a2 = fmaf(wgt, f_.x, a2); a3 = fmaf(wgt, f_.y, a3); \
        f_ = __half22float2(U.h[2]); a4 = fmaf(wgt, f_.x, a4); a5 = fmaf(wgt, f_.y, a5); \
        f_ = __half22float2(U.h[3]); a6 = fmaf(wgt, f_.x, a6); a7 = fmaf(wgt, f_.y, a7); \
    }

    // wave-uniform row-pair skip (R7): no divergence, loads stay batched
#define DCN_PAIR(wy_lo, wy_hi, cy0)                                                  \
    if (wy_lo != 0.f || wy_hi != 0.f) {                                              \
        const float wy = half_ ? (wy_hi) : (wy_lo);                                  \
        const __half* rp = bp + ((size_t)min(ybase + (cy0) + half_, 63) << 14);      \
        DCN_CELL(wy * WX.x, xi0)                                                     \
        DCN_CELL(wy * WX.y, xi1)                                                     \
        DCN_CELL(wy * WX.z, xi2)                                                     \
        if (c3) DCN_CELL(wy * WX.w, xi3)                                             \
    }

    DCN_PAIR(WY.x, WY.y, 0)
    DCN_PAIR(WY.z, WY.w, 2)
#undef DCN_PAIR
#undef DCN_CELL

    a0 += __shfl_xor(a0, 32); a1 += __shfl_xor(a1, 32);
    a2 += __shfl_xor(a2, 32); a3 += __shfl_xor(a3, 32);
    a4 += __shfl_xor(a4, 32); a5 += __shfl_xor(a5, 32);
    a6 += __shfl_xor(a6, 32); a7 += __shfl_xor(a7, 32);

    // conflict-free stage write: slot = oct + (half<<5) -> contiguous 512B/half
    const float4 v = half_ ? make_float4(a4 * inv, a5 * inv, a6 * inv, a7 * inv)
                           : make_float4(a0 * inv, a1 * inv, a2 * inv, a3 * inv);
    ((float4*)stage[wv])[oct + (half_ << 5)] = v;
    __syncthreads();

    // channel c lives at float index fi(c) = ((c>>3)<<2) | ((c&4)<<5) | (c&3)
    const int base_g = bid << 2;
    #pragma unroll
    for (int k = 0; k < 4; ++k) {
        const int idx = (k << 8) + tid;
        const int c   = idx >> 2;
        const int bs  = idx & 3;
        const int fi  = ((c >> 3) << 2) | ((c & 4) << 5) | (c & 3);
        const int gg  = base_g + bs;
        const int nn  = gg / BINS;
        const int bb2 = gg - nn * BINS;
        out[(size_t)nn * (CF * BINS) + c * BINS + bb2] = stage[bs][fi];
    }
}

// ---------------------------------------------------------------------------
// Fallback: direct (B,C,H,W) f32 gather (ws too small / unexpected shapes).
// ---------------------------------------------------------------------------
__global__ __launch_bounds__(256) void dcn_pool_fallback(const float* __restrict__ x,
                                                         const float* __restrict__ rois,
                                                         const float* __restrict__ offset,
                                                         float* __restrict__ out) {
    const int n   = blockIdx.x / BINS;
    const int bin = blockIdx.x % BINS;
    const int ph  = bin / P;
    const int pw  = bin % P;
    const int c   = threadIdx.x;

    const float* r = rois + n * 5;
    const int   batch  = (int)r[0];
    const float roi_sw = rintf(r[1]) * SCALE - 0.5f;
    const float roi_sh = rintf(r[2]) * SCALE - 0.5f;
    const float roi_w  = fmaxf((rintf(r[3]) + 1.0f) * SCALE - 0.5f - roi_sw, 0.1f);
    const float roi_h  = fmaxf((rintf(r[4]) + 1.0f) * SCALE - 0.5f - roi_sh, 0.1f);
    const float bin_w  = roi_w / 7.0f;
    const float bin_h  = roi_h / 7.0f;
    const float sub_w  = bin_w * 0.25f;
    const float sub_h  = bin_h * 0.25f;

    const float tx = offset[n * 98 + ph * 7 + pw] * 0.1f;
    const float ty = offset[n * 98 + 49 + ph * 7 + pw] * 0.1f;
    const float wstart = (float)pw * bin_w + roi_sw + tx * roi_w;
    const float hstart = (float)ph * bin_h + roi_sh + ty * roi_h;

    float sum = 0.0f;
    int   cnt = 0;
    for (int ih = 0; ih < S; ++ih) {
        for (int iw = 0; iw < S; ++iw) {
            const float wpos = wstart + (float)iw * sub_w;
            const float hpos = hstart + (float)ih * sub_h;
            if (wpos >= -0.5f && wpos <= (float)WF - 0.5f &&
                hpos >= -0.5f && hpos <= (float)HF - 0.5f) {
                const float wc_ = fminf(fmaxf(wpos, 0.0f), (float)(WF - 1));
                const float hc_ = fminf(fmaxf(hpos, 0.0f), (float)(HF - 1));
                const float fx = floorf(wc_);
                const float fy = floorf(hc_);
                const int x0 = (int)fx, x1i = (int)ceilf(wc_);
                const int y0 = (int)fy, y1i = (int)ceilf(hc_);
                const float dx = wc_ - fx, dy = hc_ - fy;
                const float* bbp = x + ((size_t)batch * CF + c) * (HF * WF);
                sum += (1.0f - dx) * (1.0f - dy) * bbp[y0 * WF + x0]
                     + dx * (1.0f - dy) * bbp[y0 * WF + x1i]
                     + (1.0f - dx) * dy * bbp[y1i * WF + x0]
                     + dx * dy * bbp[y1i * WF + x1i];
                ++cnt;
            }
        }
    }
    out[((size_t)n * CF + c) * BINS + bin] = (cnt > 0) ? (sum / (float)cnt) : 0.0f;
}

extern "C" void kernel_launch(void* const* d_in, const int* in_sizes, int n_in,
                              void* d_out, int out_size, void* d_ws, size_t ws_size,
                              hipStream_t stream) {
    const float* x      = (const float*)d_in[0];
    const float* rois   = (const float*)d_in[1];
    const float* offset = (const float*)d_in[2];
    float*       out    = (float*)d_out;

    const int N = in_sizes[1] / 5;
    const size_t need = XT_HALFS * sizeof(__half) + PAR_FLOATS * sizeof(float);

    if (ws_size >= need && N == NROI) {
        __half* xt    = (__half*)d_ws;
        float* params = (float*)(xt + XT_HALFS);
        fused_setup<<<TBLK + SETUP_BLK, 256, 0, stream>>>(x, rois, offset, xt, params);
        dcn_pool_gather<<<POOL_BLOCKS, 256, 0, stream>>>(xt, params, out);
    } else {
        dcn_pool_fallback<<<N * BINS, 256, 0, stream>>>(x, rois, offset, out);
    }
}